// Round 13
// baseline (212.932 us; speedup 1.0000x reference)
//
#include <hip/hip_runtime.h>
#include <cfloat>
#include <climits>
#include <math.h>

#define BN 16
#define QN 4096
#define GN 256
#define CN 80
#define NPART 64           // row parts in k_main (64 rows each)
#define RPP (QN / NPART)   // 64

typedef unsigned long long u64;

__device__ __forceinline__ bool lexLessF(float a, int ia, float b, int ib) {
    return (a < b) || (a == b && ia < ib);
}
// IEEE order-isomorphic u32 key (no NaNs in this data)
__device__ __forceinline__ unsigned int fkey(float f) {
    unsigned int b = __float_as_uint(f);
    return b ^ ((b >> 31) ? 0xFFFFFFFFu : 0x80000000u);
}
__device__ __forceinline__ float funkey(unsigned int k) {
    unsigned int b = k ^ ((k >> 31) ? 0x80000000u : 0xFFFFFFFFu);
    return __uint_as_float(b);
}

// ---------------- fully-fused front-end: zero | prm | class | fg | cost | selection ----------
__global__ __launch_bounds__(256) void k_main(
    const float* __restrict__ logits, const int* __restrict__ labels,
    const float* __restrict__ gtb, const float* __restrict__ gtt,
    const float* __restrict__ gtr, const float* __restrict__ imgt,
    const float* __restrict__ pboxes, const float* __restrict__ pposes,
    const float* __restrict__ img,
    float* __restrict__ costT, u64* __restrict__ rec,
    u64* __restrict__ zbase, int zn) {
#pragma clang fp contract(off)
    const int j = threadIdx.x;
    const int b = blockIdx.x >> 6;
    const int part = blockIdx.x & 63;
    const int i0 = part * RPP;

    __shared__ float Lc[RPP * CN];       // 64x80 2x focal class costs (20.5 KB)
    __shared__ float Lb[8 * GN];         // X0,Y0,X1,Y1,LOX,HIX,LOY,HIY per column (8 KB)
    __shared__ u64 Lboth[RPP][4];        // both-bitmask per row (2 KB)
    __shared__ unsigned int Lany[RPP * 4];
    __shared__ float4 Rsh[RPP][5];

    // ---- 0. zero-slice of the zero region (rowmask | rowcnt, consumed by k_dk/k_back) ----
    for (int z = blockIdx.x * 256 + j; z < zn; z += 1024 * 256) zbase[z] = 0ull;

    // ---- 1. per-column params (identical expressions) ----
    const float* g = gtb + ((size_t)(b * GN + j)) * 4;
    const float g0 = g[0], g1 = g[1], g2 = g[2], g3 = g[3];
    const float* it = imgt + ((size_t)(b * GN + j)) * 4;
    const float gn0 = g0 / it[0], gn1 = g1 / it[1], gn2 = g2 / it[2], gn3 = g3 / it[3];
    const float t0 = gtt[(b * GN + j) * 3 + 0], t1 = gtt[(b * GN + j) * 3 + 1],
                t2 = gtt[(b * GN + j) * 3 + 2];
    const float r0 = gtr[(b * GN + j) * 3 + 0], r1 = gtr[(b * GN + j) * 3 + 1],
                r2 = gtr[(b * GN + j) * 3 + 2];
    const float ga = (g2 - g0) * (g3 - g1);
    {
        float gcx = (g0 + g2) * 0.5f, gcy = (g1 + g3) * 0.5f;
        float gw = g2 - g0, gh = g3 - g1;
        float X0 = gcx - gw * 0.5f, Y0 = gcy - gh * 0.5f;
        float X1 = gcx + gw * 0.5f, Y1 = gcy + gh * 0.5f;
        float Wd = X1 - X0, Hd = Y1 - Y0;
        Lb[0 * GN + j] = X0;  Lb[1 * GN + j] = Y0;
        Lb[2 * GN + j] = X1;  Lb[3 * GN + j] = Y1;
        Lb[4 * GN + j] = gcx - 2.5f * Wd; Lb[5 * GN + j] = gcx + 2.5f * Wd;
        Lb[6 * GN + j] = gcy - 2.5f * Hd; Lb[7 * GN + j] = gcy + 2.5f * Hd;
    }
    const int lab = labels[b * GN + j];

    // ---- 2. class focal for the block's 64 rows x 80 classes (contiguous 20 KB span) ----
    const float* lbase = logits + ((size_t)(b * QN + i0)) * CN;
#pragma unroll
    for (int q = 0; q < 20; q++) {
        int idx = q * 256 + j;
        float x = lbase[idx];
        float e = (float)exp(-(double)x);
        float pr = 1.0f / (1.0f + e);
        float om = 1.0f - pr;
        float lneg = (float)log((double)(om + 1e-8f));
        float lpos = (float)log((double)(pr + 1e-8f));
        float neg = (0.75f * (pr * pr)) * (-lneg);
        float pos = (0.25f * (om * om)) * (-lpos);
        Lc[idx] = 2.0f * (pos - neg);    // pre-doubled: 2*cc is exact in f32
    }

    // ---- 3. row staging ----
    if (threadIdx.x < RPP) {
        const int i = i0 + threadIdx.x;
        const float im0 = img[b * 4 + 0], im1 = img[b * 4 + 1];
        const float im2 = img[b * 4 + 2], im3 = img[b * 4 + 3];
        const float4 bx = *reinterpret_cast<const float4*>(pboxes + ((size_t)(b * QN + i)) * 4);
        const float b0 = bx.x, b1 = bx.y, b2 = bx.z, b3 = bx.w;
        const float2* pp2 = reinterpret_cast<const float2*>(pposes + ((size_t)(b * QN + i)) * 6);
        const float2 q0 = pp2[0], q1 = pp2[1], q2 = pp2[2];
        const float bn0 = b0 / im0, bn1 = b1 / im1, bn2 = b2 / im2, bn3 = b3 / im3;
        const float a1 = (b2 - b0) * (b3 - b1);
        const float ax = (b0 + b2) * 0.5f, ay = (b1 + b3) * 0.5f;
        Rsh[threadIdx.x][0] = make_float4(b0, b1, b2, b3);
        Rsh[threadIdx.x][1] = make_float4(bn0, bn1, bn2, bn3);
        Rsh[threadIdx.x][2] = make_float4(ax, ay, a1, 0.0f);
        Rsh[threadIdx.x][3] = make_float4(q0.x, q0.y, q1.x, q1.y);
        Rsh[threadIdx.x][4] = make_float4(q2.x, q2.y, 0.0f, 0.0f);
    }
    __syncthreads();

    // ---- 4. fg + both-bits: thread t -> row t&63, gt chunk t>>6 (64 gts) ----
    {
        const int r = threadIdx.x & 63, ch = threadIdx.x >> 6;
        const float axr = Rsh[r][2].x, ayr = Rsh[r][2].y;
        bool any = false;
        u64 bothbits = 0;
        const int jb = ch * 64;
#pragma unroll 8
        for (int m = 0; m < 64; m++) {
            int jj = jb + m;
            bool ib = (axr > Lb[0 * GN + jj]) && (axr < Lb[2 * GN + jj]) &&
                      (ayr > Lb[1 * GN + jj]) && (ayr < Lb[3 * GN + jj]);
            bool ic = (axr > Lb[4 * GN + jj]) && (axr < Lb[5 * GN + jj]) &&
                      (ayr > Lb[6 * GN + jj]) && (ayr < Lb[7 * GN + jj]);
            any |= (ib || ic);
            if (ib && ic) bothbits |= (1ull << m);
        }
        Lany[r * 4 + ch] = any ? 1u : 0u;
        Lboth[r][ch] = bothbits;
    }
    __syncthreads();
    if (threadIdx.x < RPP) {
        unsigned int a = 0;
#pragma unroll
        for (int c = 0; c < 4; c++) a |= Lany[threadIdx.x * 4 + c];
        Rsh[threadIdx.x][2].w = a ? 0.0f : 10000.0f;   // fgadd folded into row record
    }
    __syncthreads();

    // ---- 5. cost + selection main loop ----
    float* CT = costT + ((size_t)(b * QN) + i0) * GN + j;
    const int jw = j >> 6, jb63 = j & 63;

    u64 ck[5]; float iv[5];
#pragma unroll
    for (int k = 0; k < 5; k++) { ck[k] = ~0ull; iv[k] = -1.0f; }

    for (int r = 0; r < RPP; r++) {
        const int i = i0 + r;
        const float4 R0 = Rsh[r][0];
        const float4 R1 = Rsh[r][1];
        const float4 R2 = Rsh[r][2];
        const float4 R3 = Rsh[r][3];
        const float4 R4 = Rsh[r][4];
        const float b0 = R0.x, b1 = R0.y, b2 = R0.z, b3 = R0.w;
        const float bn0 = R1.x, bn1 = R1.y, bn2 = R1.z, bn3 = R1.w;
        const float a1 = R2.z, fgadd = R2.w;
        const float p0 = R3.x, p1 = R3.y, p2 = R3.z, p3 = R3.w;
        const float p4 = R4.x, p5 = R4.y;
        const float cc2 = Lc[r * CN + lab];
        const bool both = (Lboth[r][jw] >> jb63) & 1;

        // iou / giou (f32, reference op order)
        float ltx = fmaxf(b0, g0), lty = fmaxf(b1, g1);
        float rbx = fminf(b2, g2), rby = fminf(b3, g3);
        float w = fmaxf(rbx - ltx, 0.0f), h = fmaxf(rby - lty, 0.0f);
        float inter = w * h;
        float uni = (a1 + ga) - inter;
        float iou = inter / uni;
        float eltx = fminf(b0, g0), elty = fminf(b1, g1);
        float erbx = fmaxf(b2, g2), erby = fmaxf(b3, g3);
        float ew = fmaxf(erbx - eltx, 0.0f), eh = fmaxf(erby - elty, 0.0f);
        float earea = ew * eh;
        float giou = iou - (earea - uni) / earea;

        // normalized bbox L1 (sequential f32)
        float cb = fabsf(bn0 - gn0);
        cb = cb + fabsf(bn1 - gn1);
        cb = cb + fabsf(bn2 - gn2);
        cb = cb + fabsf(bn3 - gn3);
        // pose L1
        float ct = fabsf(p0 - t0); ct = ct + fabsf(p1 - t1); ct = ct + fabsf(p2 - t2);
        float cr = fabsf(p3 - r0); cr = cr + fabsf(p4 - r1); cr = cr + fabsf(p5 - r2);

        float d = 5.0f * cb;
        d = d + cc2;
        d = d + 2.0f * (-giou);
        d = d + (both ? 0.0f : 100.0f);
        d = d + ct;
        d = d + cr;
        d = d + fgadd;

        CT[(size_t)r * GN] = d;

        // bottom-5 via u64 key cascade (order-isomorphic to (cost,i) lex)
        u64 key = ((u64)fkey(d) << 32) | (unsigned int)i;
        if (key < ck[4]) {
#pragma unroll
            for (int k = 0; k < 5; k++) {
                u64 mn = key < ck[k] ? key : ck[k];
                u64 mx = key < ck[k] ? ck[k] : key;
                ck[k] = mn; key = mx;
            }
        }
        // top-5 iou via max/min network
        if (iou > iv[4]) {
            float fv = iou;
#pragma unroll
            for (int k = 0; k < 5; k++) {
                float mx = fmaxf(fv, iv[k]);
                fv = fminf(fv, iv[k]);
                iv[k] = mx;
            }
        }
    }

    // pack one 64B record and store as 4x16B (full-line write)
    const int col = b * GN + j;
    u64 buf[8];
#pragma unroll
    for (int k = 0; k < 5; k++) buf[k] = ck[k];
    float* bf = (float*)(buf + 5);
#pragma unroll
    for (int k = 0; k < 5; k++) bf[k] = iv[k];
    bf[5] = 0.0f;                                   // pad -> full 64B line
    ulonglong2* dst = (ulonglong2*)(rec + (((size_t)col * NPART) + part) * 8);
    const ulonglong2* src = (const ulonglong2*)buf;
    dst[0] = src[0]; dst[1] = src[1]; dst[2] = src[2]; dst[3] = src[3];
}

// ---------------- merge parts (wave butterfly), dk, rowmask, rowcnt, staleAmin init ----------
// NPART=64: exactly one record per lane; no pre-merge needed.
__global__ __launch_bounds__(256) void k_dk(const u64* __restrict__ rec,
                                            float* __restrict__ candcv, int* __restrict__ candci,
                                            int* __restrict__ dkArr, u64* __restrict__ rowmask,
                                            int* __restrict__ rowcnt,
                                            u64* __restrict__ staleAmin) {
#pragma clang fp contract(off)
    const int lane = threadIdx.x & 63;
    const int colIdx = blockIdx.x * 4 + (threadIdx.x >> 6);   // 4 waves/block
    const int b = colIdx >> 8, j = colIdx & 255;
    const u64* R0 = rec + (((size_t)colIdx * NPART) + lane) * 8;
    u64 rv[5]; float fr[5];
    const float* F0 = (const float*)(R0 + 5);
#pragma unroll
    for (int k = 0; k < 5; k++) { rv[k] = R0[k]; fr[k] = F0[k]; }
    for (int off = 1; off < 64; off <<= 1) {
        u64 ov[5]; float of[5];
#pragma unroll
        for (int m = 0; m < 5; m++) {
            ov[m] = __shfl_xor(rv[m], off, 64);
            of[m] = __shfl_xor(fr[m], off, 64);
        }
#pragma unroll
        for (int m = 0; m < 5; m++) {
            u64 key = ov[m];
            if (key < rv[4]) {
#pragma unroll
                for (int k = 0; k < 5; k++) {
                    u64 mn = key < rv[k] ? key : rv[k];
                    u64 mx = key < rv[k] ? rv[k] : key;
                    rv[k] = mn; key = mx;
                }
            }
            float fv = of[m];
            if (fv > fr[4]) {
#pragma unroll
                for (int k = 0; k < 5; k++) {
                    float mx = fmaxf(fv, fr[k]);
                    fv = fminf(fv, fr[k]);
                    fr[k] = mx;
                }
            }
        }
    }

    if (lane == 0) {
        float sum = ((((fr[0] + fr[1]) + fr[2]) + fr[3]) + fr[4]);  // desc order, sequential
        int dk = (int)sum;
        if (dk < 1) dk = 1;
        if (dk > 5) dk = 5;
        dkArr[colIdx] = dk;
        staleAmin[colIdx] = ~0ull;
#pragma unroll
        for (int k = 0; k < 5; k++) {
            candcv[(size_t)colIdx * 5 + k] = funkey((unsigned int)(rv[k] >> 32));
            candci[(size_t)colIdx * 5 + k] = (int)(unsigned int)(rv[k] & 0xFFFFFFFFull);
        }
        for (int k = 0; k < dk; k++) {
            int i = (int)(unsigned int)(rv[k] & 0xFFFFFFFFull);
            atomicOr(&rowmask[((size_t)(b * QN + i)) * 4 + (j >> 6)], 1ull << (j & 63));
            atomicAdd(&rowcnt[b * QN + i], 1);
        }
    }
}

// ---------------- per-batch back-end: one block per batch, 1024 threads ------------------
// All cross-stage dependencies intra-batch -> __syncthreads. colcnt is LDS (final before
// phase 2 -> old racy-monotone logic becomes exact). Assignment rows (rowcnt==0) are
// disjoint from candidate rows (rowcnt>=1), so phase-4 ORs don't perturb matched-col checks.
__global__ __launch_bounds__(1024) void k_back(const float* __restrict__ costT,
                                               const int* __restrict__ rowcnt,
                                               u64* __restrict__ rowmask,
                                               const float* __restrict__ candcv,
                                               const int* __restrict__ candci,
                                               const int* __restrict__ dkArr,
                                               u64* __restrict__ staleAmin,
                                               int* __restrict__ out) {
    const int b = blockIdx.x;
    const int t = threadIdx.x;
    const int lane = t & 63;

    __shared__ int colcntS[GN];
    __shared__ u64 aminS[GN];
    __shared__ int fbCountS;
    __shared__ int fbLS[GN];
    __shared__ u64 red[1024];

    if (t < GN) { colcntS[t] = 0; aminS[t] = ~0ull; }
    if (t == 0) fbCountS = 0;
    __syncthreads();

    // ---- phase 1: row side — detect, LDS colcnt, wave-cooperative stale fix ----
    for (int s = 0; s < 4; s++) {
        const int i = s * 1024 + t;
        const int cnt = rowcnt[b * QN + i];
        if (cnt == 1) {
            const u64* rm = rowmask + ((size_t)(b * QN + i)) * 4;
            u64 w0 = rm[0], w1 = rm[1], w2 = rm[2], w3 = rm[3];
            u64 w; int base;
            if (w0) { w = w0; base = 0; }
            else if (w1) { w = w1; base = 64; }
            else if (w2) { w = w2; base = 128; }
            else { w = w3; base = 192; }
            int jj = base + (__ffsll((long long)w) - 1);
            atomicAdd(&colcntS[jj], 1);
        }
        u64 bal = __ballot(cnt > 1);
        while (bal) {
            const int L = __ffsll((long long)bal) - 1;
            bal &= bal - 1;
            const int iL = (i & ~63) | L;
            const float* cb = costT + ((size_t)(b * QN) + iL) * GN;   // contiguous row
            float best = FLT_MAX; int bj = GN;
            for (int k = 0; k < GN; k += 64) {
                int jj = k + lane;
                float v = cb[jj];
                if (lexLessF(v, jj, best, bj)) { best = v; bj = jj; }
            }
            for (int off = 32; off > 0; off >>= 1) {
                float ov = __shfl_down(best, off, 64);
                int oj = __shfl_down(bj, off, 64);
                if (lexLessF(ov, oj, best, bj)) { best = ov; bj = oj; }
            }
            if (lane == 0) {
                u64* rm = rowmask + ((size_t)(b * QN + iL)) * 4;
                rm[0] = ((bj >> 6) == 0) ? (1ull << (bj & 63)) : 0ull;
                rm[1] = ((bj >> 6) == 1) ? (1ull << (bj & 63)) : 0ull;
                rm[2] = ((bj >> 6) == 2) ? (1ull << (bj & 63)) : 0ull;
                rm[3] = ((bj >> 6) == 3) ? (1ull << (bj & 63)) : 0ull;
                atomicAdd(&colcntS[bj], 1);
                float pv = best + 100000.0f;
                u64 key = ((u64)fkey(pv) << 32) | (unsigned int)iL;
                atomicMin(&staleAmin[b * GN + bj], key);
            }
        }
    }
    __syncthreads();

    // ---- phase 2: candidate assign vs FINAL colcnt (threads 0..255) ----
    if (t < GN) {
        const int col = b * GN + t;
        if (colcntS[t] == 0) {
            bool found = false;
            u64 best = ~0ull;
#pragma unroll
            for (int k = 0; k < 5; k++) {
                if (!found) {
                    int i = candci[(size_t)col * 5 + k];
                    if (rowcnt[b * QN + i] == 0) {
                        best = ((u64)fkey(candcv[(size_t)col * 5 + k]) << 32) | (unsigned int)i;
                        found = true;
                    }
                }
            }
            if (found) {
                aminS[t] = best;
            } else {
                int e = atomicAdd(&fbCountS, 1);
                fbLS[e] = t;
            }
        }
    }
    __syncthreads();

    // ---- phase 3: fallback scans (whole block per entry) ----
    const int nfb = fbCountS;
    for (int e = 0; e < nfb; e++) {
        const int jc = fbLS[e];
        const float* C = costT + ((size_t)(b * QN)) * GN + jc;
        u64 best = ~0ull;
#pragma unroll
        for (int s = 0; s < 4; s++) {
            int r = s * 1024 + t;
            if (rowcnt[b * QN + r] == 0) {
                float v = C[(size_t)r * GN];
                u64 key = ((u64)fkey(v) << 32) | (unsigned int)r;
                best = key < best ? key : best;
            }
        }
        red[t] = best;
        __syncthreads();
        for (int s2 = 512; s2 > 0; s2 >>= 1) {
            if (t < s2) { u64 o = red[t + s2]; if (o < red[t]) red[t] = o; }
            __syncthreads();
        }
        if (t == 0) aminS[jc] = red[0];
        __syncthreads();
    }

    // ---- phase 4: apply assignments + outcols (threads 0..255) ----
    if (t < GN) {
        const int col = b * GN + t;
        int* o = out + (size_t)2 * BN * QN + col;
        if (colcntS[t] == 0) {
            u64 key = aminS[t];
            int r = (int)(unsigned int)(key & 0xFFFFFFFFull);
            atomicOr(&rowmask[((size_t)(b * QN + r)) * 4 + (t >> 6)], 1ull << (t & 63));
            *o = r;
        } else {
            const u64 bit = 1ull << (t & 63);
            const int w = t >> 6;
            float best = FLT_MAX; int bi = INT_MAX;
            const int dk = dkArr[col];
            for (int k = 0; k < 5; k++) {
                if (k < dk) {
                    int i = candci[(size_t)col * 5 + k];
                    if (rowmask[((size_t)(b * QN + i)) * 4 + w] & bit) {
                        float pv = candcv[(size_t)col * 5 + k] + 100000.0f;
                        if (lexLessF(pv, i, best, bi)) { best = pv; bi = i; }
                    }
                }
            }
            const u64 sk = staleAmin[col];
            if (sk != ~0ull) {
                float pv = funkey((unsigned int)(sk >> 32));
                int ei = (int)(unsigned int)(sk & 0xFFFFFFFFull);
                if (lexLessF(pv, ei, best, bi)) { best = pv; bi = ei; }
            }
            *o = (bi == INT_MAX) ? 0 : bi;
        }
    }
    __syncthreads();

    // ---- phase 5: outrows (final rowmask incl. this block's ORs) ----
    for (int s = 0; s < 4; s++) {
        const int i = s * 1024 + t;
        const u64* rm = rowmask + ((size_t)(b * QN + i)) * 4;
        u64 w0 = rm[0], w1 = rm[1], w2 = rm[2], w3 = rm[3];
        int sel = (w0 | w1 | w2 | w3) ? 1 : 0;
        int g = 0;
        if (w0) g = __ffsll((long long)w0) - 1;
        else if (w1) g = 64 + __ffsll((long long)w1) - 1;
        else if (w2) g = 128 + __ffsll((long long)w2) - 1;
        else if (w3) g = 192 + __ffsll((long long)w3) - 1;
        out[(size_t)b * QN + i] = sel;
        out[(size_t)BN * QN + (size_t)b * QN + i] = g;
    }
}

extern "C" void kernel_launch(void* const* d_in, const int* in_sizes, int n_in,
                              void* d_out, int out_size, void* d_ws, size_t ws_size,
                              hipStream_t stream) {
    const float* logits = (const float*)d_in[0];
    const float* pboxes = (const float*)d_in[1];
    const float* pposes = (const float*)d_in[2];
    const int* labels = (const int*)d_in[3];
    const float* gtb = (const float*)d_in[4];
    const float* gtt = (const float*)d_in[5];
    const float* gtr = (const float*)d_in[6];
    const float* img = (const float*)d_in[7];
    const float* imgt = (const float*)d_in[8];
    int* out = (int*)d_out;

    char* p = (char*)d_ws;
    float* costT = (float*)p;            p += (size_t)BN * QN * GN * 4;        // 64 MiB
    u64* rec = (u64*)p;                  p += (size_t)BN * GN * NPART * 64;    // 16 MiB (64B/record)
    // ---- zero region: rowmask | rowcnt (contiguous) ----
    u64* rowmask = (u64*)p;              size_t rb = (size_t)BN * QN * 4 * 8; p += rb;  // 2 MiB
    int* rowcnt = (int*)p;               p += (size_t)BN * QN * 4;             // 256 KiB
    // ---- end zero region ----
    float* candcv = (float*)p;           p += (size_t)BN * GN * 5 * 4;         // 80 KiB
    int* candci = (int*)p;               p += (size_t)BN * GN * 5 * 4;         // 80 KiB
    int* dkArr = (int*)p;                p += (size_t)BN * GN * 4;             // 16 KiB
    u64* staleAmin = (u64*)p;            p += (size_t)BN * GN * 8;             // 32 KiB (init in k_dk)

    // zero region size in u64: rowmask(2MiB) + rowcnt(256KiB)
    int zn = (int)((rb + (size_t)BN * QN * 4) / 8);   // = 294912

    k_main<<<BN * NPART, 256, 0, stream>>>(logits, labels, gtb, gtt, gtr, imgt,
                                           pboxes, pposes, img, costT, rec,
                                           (u64*)rowmask, zn);
    k_dk<<<BN * GN / 4, 256, 0, stream>>>(rec, candcv, candci, dkArr, rowmask, rowcnt,
                                          staleAmin);
    k_back<<<BN, 1024, 0, stream>>>(costT, rowcnt, rowmask, candcv, candci, dkArr,
                                    staleAmin, out);
}